// Round 7
// baseline (190.397 us; speedup 1.0000x reference)
//
#include <hip/hip_runtime.h>
#include <hip/hip_bf16.h>

// B=2, N=2048, D=1024, H=16, DH=64. Output fp32; inputs runtime-detected and
// converted once. R12: qkv/oproj staging via global_load_lds width=16 + XOR
// chunk swizzle; attn diagonal-tile specialization.
// R14: attn ALiBi reach cap (sl2*j>46 tiles skipped; 0.54x work).
// R16/R18: LPT schedules. Balance worked (sum-bound 48 -> ~22us) but attn
// pinned at ~41us in BOTH -> model: T_CU = max(sum*0.6, longest_block*1.3).
// The 32-tile blocks' serial chain (barrier->stage->barrier->compute per
// tile) is the binding constraint; no schedule can fix it.
// R19: double-buffered K/V LDS (2x9KB per operand, 36KB block total, still
// 4 blocks/CU). Per tile: compute(buf[cur]) || ds_write(buf[cur^1]) ->
// ONE barrier (was two + serialized stage). Global loads issued one full
// iteration ahead (reg prefetch depth 1). Chain 32x1.3 -> 32x~0.85us.
//
// ws (bf16 elems): Q@0(4M), K@4M, Vt@8M, Xc/AO@12M (shared), WqT@16M..WoT@19M,
// boc@20M. ~40MB.

typedef __bf16 bf16x8 __attribute__((ext_vector_type(8)));
typedef float f32x4 __attribute__((ext_vector_type(4)));
typedef short s4 __attribute__((ext_vector_type(4)));      // k16 MFMA A/B frag
typedef unsigned short ushort_t;

#define MFMA_16x16x32(a, b, c) __builtin_amdgcn_mfma_f32_16x16x32_bf16(a, b, c, 0, 0, 0)
#define MFMA16(a, b, c) __builtin_amdgcn_mfma_f32_16x16x16bf16_1k(a, b, c, 0, 0, 0)

__device__ __forceinline__ ushort_t f2bf(float f) {
    __hip_bfloat16 h = __float2bfloat16(f);
    return __builtin_bit_cast(ushort_t, h);
}
__device__ __forceinline__ float bf2f(ushort_t u) {
    unsigned x = ((unsigned)u) << 16;
    return __builtin_bit_cast(float, x);
}

// async global->LDS, 16B/lane; LDS dest = wave-uniform base + lane*16.
__device__ __forceinline__ void gl_lds16(const ushort_t* g, ushort_t* l) {
    __builtin_amdgcn_global_load_lds(
        (const __attribute__((address_space(1))) void*)g,
        (__attribute__((address_space(3))) void*)l, 16, 0, 0);
}

__device__ __forceinline__ unsigned detect_fp32(const void* wp) {
    const ushort_t* w = (const ushort_t*)wp;
    unsigned c = 0;
    #pragma unroll
    for (int i = 0; i < 128; ++i) c += (((w[i] >> 7) & 0xFF) >= 0x7F) ? 1u : 0u;
    return (c > 8) ? 1u : 0u;
}

__device__ __forceinline__ uint4 load8(const void* p, size_t idx, unsigned flag) {
    if (flag) {
        const float* f = (const float*)p + idx;
        float4 a = *(const float4*)f;
        float4 b = *(const float4*)(f + 4);
        ushort_t u[8] = { f2bf(a.x), f2bf(a.y), f2bf(a.z), f2bf(a.w),
                          f2bf(b.x), f2bf(b.y), f2bf(b.z), f2bf(b.w) };
        return *(uint4*)u;
    }
    return *(const uint4*)((const ushort_t*)p + idx);
}

// ---- R18 XCD-grouped LPT schedule for attn: slot -> (qb<<5)|bh ----
struct Sched { unsigned short v[1024]; };
constexpr Sched make_sched() {
    Sched s{};
    int jc[16] = {1, 1, 2, 2, 3, 4, 6, 8, 12, 16, 23, 32, 32, 32, 32, 32};
    int grp[8][4] = {
        {11,      12,      0,       2},
        {13,      14,      1,       3},
        {16 + 11, 16 + 12, 16 + 0,  16 + 2},
        {16 + 13, 16 + 14, 16 + 1,  16 + 3},
        {15,      10,      5,       4},
        {16 + 15, 16 + 10, 16 + 5,  16 + 4},
        {9,       8,       7,       6},
        {16 + 9,  16 + 8,  16 + 7,  16 + 6},
    };
    for (int x = 0; x < 8; ++x) {
        int items[128] = {};
        int n = 0;
        for (int w = 32; w >= 1; --w)                   // counting sort, desc
            for (int gi = 0; gi < 4; ++gi) {
                int bh = grp[x][gi], h = bh & 15;
                for (int qb = 0; qb < 32; ++qb) {
                    int wi = (qb + 1 < jc[h]) ? (qb + 1) : jc[h];
                    if (wi == w) items[n++] = (qb << 5) | bh;
                }
            }
        for (int t = 0; t < 128; ++t) {
            int r = t >> 5, p = t & 31;
            int cu = (r & 1) ? (31 - p) : p;            // serpentine
            s.v[r * 256 + cu * 8 + x] = (unsigned short)items[t];
        }
    }
    return s;
}
__constant__ Sched g_sched = make_sched();

// ---------------- convert X + bias ----------------
__global__ __launch_bounds__(256) void convert_x(
    const void* __restrict__ X, const void* __restrict__ Wq, const void* __restrict__ bo,
    ushort_t* __restrict__ Xc, ushort_t* __restrict__ boc)
{
    const unsigned flag = detect_fp32(Wq);
    const int blk = blockIdx.x;
    if (blk < 2048) {
        size_t idx = (size_t)blk * 2048 + (size_t)threadIdx.x * 8;
        *(uint4*)(Xc + idx) = load8(X, idx, flag);
    } else {
        size_t idx = (size_t)threadIdx.x * 8;
        if (idx < 1024) *(uint4*)(boc + idx) = load8(bo, idx, flag);
    }
}

// ---------------- transpose weights -> WT[n][k] ----------------
__global__ __launch_bounds__(256) void transpose_w(
    const void* __restrict__ Wq, const void* __restrict__ Wk,
    const void* __restrict__ Wv, const void* __restrict__ Wo,
    ushort_t* __restrict__ WqT, ushort_t* __restrict__ WkT,
    ushort_t* __restrict__ WvT, ushort_t* __restrict__ WoT)
{
    __shared__ ushort_t T[64][72];
    const unsigned flag = detect_fp32(Wq);
    const int z = blockIdx.z;
    const void* W = (z == 0) ? Wq : ((z == 1) ? Wk : ((z == 2) ? Wv : Wo));
    ushort_t* WT = (z == 0) ? WqT : ((z == 1) ? WkT : ((z == 2) ? WvT : WoT));

    const int k0 = blockIdx.y * 64, n0 = blockIdx.x * 64;
    const int r = threadIdx.x >> 2, c = (threadIdx.x & 3) * 16;

    *(uint4*)&T[r][c]     = load8(W, (size_t)(k0 + r) * 1024 + n0 + c,     flag);
    *(uint4*)&T[r][c + 8] = load8(W, (size_t)(k0 + r) * 1024 + n0 + c + 8, flag);
    __syncthreads();
    ushort_t tmp[16];
    #pragma unroll
    for (int j = 0; j < 16; ++j) tmp[j] = T[c + j][r];
    *(uint4*)(WT + (size_t)(n0 + r) * 1024 + k0 + c)     = *(uint4*)&tmp[0];
    *(uint4*)(WT + (size_t)(n0 + r) * 1024 + k0 + c + 8) = *(uint4*)&tmp[8];
}

// ---------------- QKV projection GEMM, 128x128, global_load_lds staging ----------------
__global__ __launch_bounds__(256) void qkv_gemm(
    const ushort_t* __restrict__ X, const ushort_t* __restrict__ WqT,
    const ushort_t* __restrict__ WkT, const ushort_t* __restrict__ WvT,
    ushort_t* __restrict__ Q, ushort_t* __restrict__ K, ushort_t* __restrict__ Vt)
{
    __shared__ ushort_t As[128 * 32];
    __shared__ ushort_t Bs[128 * 32];

    const int z = blockIdx.z;
    const ushort_t* WT = (z == 0) ? WqT : ((z == 1) ? WkT : WvT);

    const int tid  = threadIdx.x;
    const int m0   = blockIdx.y * 128, n0 = blockIdx.x * 128;
    const int lane = tid & 63, wv = tid >> 6;
    const int quad = lane >> 4, l15 = lane & 15;
    const int wm = (wv & 1) * 64, wn = (wv >> 1) * 64;

    const int lrow = lane >> 2;                         // 0..15
    const int schk = (lane & 3) ^ ((lane >> 3) & 3);    // swizzled source chunk
    const int ra0_ = wv * 16 + lrow;                    // issue-0 row
    ushort_t* aB0 = As + wv * 512;                      // wave-uniform LDS bases
    ushort_t* aB1 = As + 2048 + wv * 512;
    ushort_t* bB0 = Bs + wv * 512;
    ushort_t* bB1 = Bs + 2048 + wv * 512;
    const int sp = quad ^ ((l15 >> 1) & 3);             // read chunk position

    f32x4 acc[4][4] = {};

    for (int kt = 0; kt < 32; ++kt) {
        const int k0 = kt * 32;
        __syncthreads();
        gl_lds16(X  + (size_t)(m0 + ra0_)      * 1024 + k0 + schk * 8, aB0);
        gl_lds16(X  + (size_t)(m0 + 64 + ra0_) * 1024 + k0 + schk * 8, aB1);
        gl_lds16(WT + (size_t)(n0 + ra0_)      * 1024 + k0 + schk * 8, bB0);
        gl_lds16(WT + (size_t)(n0 + 64 + ra0_) * 1024 + k0 + schk * 8, bB1);
        __syncthreads();   // compiler emits vmcnt(0) drain -> LDS data visible

        bf16x8 af[4], bfr[4];
        #pragma unroll
        for (int t = 0; t < 4; ++t) {
            af[t]  = *(const bf16x8*)(As + (wm + t * 16 + l15) * 32 + sp * 8);
            bfr[t] = *(const bf16x8*)(Bs + (wn + t * 16 + l15) * 32 + sp * 8);
        }
        #pragma unroll
        for (int mt = 0; mt < 4; ++mt)
            #pragma unroll
            for (int nt = 0; nt < 4; ++nt)
                acc[mt][nt] = MFMA_16x16x32(af[mt], bfr[nt], acc[mt][nt]);
    }

    #pragma unroll
    for (int mt = 0; mt < 4; ++mt) {
        #pragma unroll
        for (int nt = 0; nt < 4; ++nt) {
            if (z == 2) {
                int c  = n0 + wn + nt * 16 + l15;
                int h  = c >> 6, dh = c & 63;
                int mA = m0 + wm + mt * 16 + quad * 4;
                int b  = mA >> 11, nseq = mA & 2047;
                ushort_t pk[4];
                #pragma unroll
                for (int r = 0; r < 4; ++r) pk[r] = f2bf(acc[mt][nt][r]);
                *(ushort2*)(Vt + ((size_t)((b * 16 + h) * 64 + dh)) * 2048 + nseq)     = *(ushort2*)&pk[0];
                *(ushort2*)(Vt + ((size_t)((b * 16 + h) * 64 + dh)) * 2048 + nseq + 2) = *(ushort2*)&pk[2];
            } else {
                ushort_t* dst = (z == 0) ? Q : K;
                #pragma unroll
                for (int r = 0; r < 4; ++r) {
                    int m = m0 + wm + mt * 16 + quad * 4 + r;
                    int c = n0 + wn + nt * 16 + l15;
                    int b = m >> 11, nseq = m & 2047;
                    int h = c >> 6, dh = c & 63;
                    dst[((size_t)((b * 16 + h) * 2048 + nseq)) * 64 + dh] = f2bf(acc[mt][nt][r]);
                }
            }
        }
    }
}

// ---------------- MFMA flash attention: double-buffered K/V LDS ----------------
// grid 1024 flat, block 256 = 4 waves; (bh,qb) from g_sched (XCD-grouped LPT).
// R19: 2-deep pipeline. Iter jt: compute from buf[jt&1] || ds_write buf[jt+1&1]
// (regs loaded one iter earlier) || issue global loads for jt+2 -> ONE barrier.
// Hazard check: iter jt writes buf[(jt+1)&1], which was last READ in iter
// jt-1; the barrier at end of jt-1 orders read-before-overwrite. The write
// is read in jt+1, ordered by the barrier at end of jt.
__global__ __launch_bounds__(256) void attn_kernel(
    const ushort_t* __restrict__ Q, const ushort_t* __restrict__ K,
    const ushort_t* __restrict__ Vt, ushort_t* __restrict__ AO)
{
    __shared__ ushort_t Ks[2][64 * 72];   // [buf][j][d], stride 72
    __shared__ ushort_t Vs[2][64 * 72];   // [buf][d][j], stride 72

    const int tid  = threadIdx.x;
    const int wv   = tid >> 6, lane = tid & 63;
    const int quad = lane >> 4, l15 = lane & 15;
    const int item = g_sched.v[blockIdx.x];
    const int bh   = item & 31, h = bh & 15, b = bh >> 4;
    const int qb   = item >> 5;
    const int iw   = qb * 64 + wv * 16;
    const int i_   = iw + l15;

    const ushort_t* Qh = Q  + (size_t)bh * 2048 * 64;
    const ushort_t* Kh = K  + (size_t)bh * 2048 * 64;
    const ushort_t* Vh = Vt + (size_t)bh * 64 * 2048;

    const float LOG2E = 1.44269504088896340736f;
    const float sl2 = exp2f(-0.5f * (float)(h + 1)) * LOG2E;
    const float c1  = 0.125f * LOG2E;

    // ALiBi reach cap: j-tiles with sl2*(tile start) > 46 only produce
    // exp2 underflow (relative contribution < 2^-27) -> skip them.
    const int jcap   = (int)(46.0f / (sl2 * 64.0f)) + 1;
    const int ntiles = min(qb + 1, jcap);

    bf16x8 qf0 = *(const bf16x8*)(Qh + (size_t)(iw + l15) * 64 + quad * 8);
    bf16x8 qf1 = *(const bf16x8*)(Qh + (size_t)(iw + l15) * 64 + 32 + quad * 8);

    s4 onesf;
    #pragma unroll
    for (int e = 0; e < 4; ++e) onesf[e] = (short)0x3F80;

    // per-lane bias base: -sl2*(quad*4+r); per-subtile only add -sl2*j0s.
    float nb[4];
    #pragma unroll
    for (int r = 0; r < 4; ++r) nb[r] = -sl2 * (float)(quad * 4 + r);

    f32x4 accv[4] = {};
    f32x4 accl = {};

    const int sr = tid >> 2, sc = (tid & 3) * 16;

    // tile 0: load -> buf0 (prologue)
    uint4 ka0 = *(const uint4*)(Kh + (size_t)sr * 64 + sc);
    uint4 ka1 = *(const uint4*)(Kh + (size_t)sr * 64 + sc + 8);
    uint4 va0 = *(const uint4*)(Vh + (size_t)sr * 2048 + sc);
    uint4 va1 = *(const uint4*)(Vh + (size_t)sr * 2048 + sc + 8);
    *(uint4*)(Ks[0] + sr * 72 + sc)     = ka0;
    *(uint4*)(Ks[0] + sr * 72 + sc + 8) = ka1;
    *(uint4*)(Vs[0] + sr * 72 + sc)     = va0;
    *(uint4*)(Vs[0] + sr * 72 + sc + 8) = va1;
    if (1 < ntiles) {        // prefetch tile 1 into regs
        ka0 = *(const uint4*)(Kh + (size_t)(64 + sr) * 64 + sc);
        ka1 = *(const uint4*)(Kh + (size_t)(64 + sr) * 64 + sc + 8);
        va0 = *(const uint4*)(Vh + (size_t)sr * 2048 + 64 + sc);
        va1 = *(const uint4*)(Vh + (size_t)sr * 2048 + 64 + sc + 8);
    }
    __syncthreads();

    const ushort_t* Kc;
    const ushort_t* Vc;

    auto subtile = [&](int jt, int js, bool masked) {
        const int j0s = jt * 64 + js * 16;
        const float bj = -sl2 * (float)j0s;   // wave-uniform per subtile
        f32x4 sT = {};
        bf16x8 kf0 = *(const bf16x8*)(Kc + (js * 16 + l15) * 72 + quad * 8);
        bf16x8 kf1 = *(const bf16x8*)(Kc + (js * 16 + l15) * 72 + 32 + quad * 8);
        sT = MFMA_16x16x32(kf0, qf0, sT);
        sT = MFMA_16x16x32(kf1, qf1, sT);
        unsigned u[4];
        #pragma unroll
        for (int r = 0; r < 4; ++r) {
            float p = exp2f(fmaf(sT[r], c1, nb[r] + bj));
            if (masked && (j0s + quad * 4 + r) > i_) p = 0.0f;
            u[r] = __builtin_bit_cast(unsigned, p) + 0x8000u;
        }
        uint2 dd = { (u[0] >> 16) | (u[1] & 0xFFFF0000u),
                     (u[2] >> 16) | (u[3] & 0xFFFF0000u) };
        s4 pf = __builtin_bit_cast(s4, dd);
        accl = MFMA16(onesf, pf, accl);
        #pragma unroll
        for (int dt = 0; dt < 4; ++dt) {
            s4 vf = *(const s4*)(Vc + (dt * 16 + l15) * 72 + js * 16 + quad * 4);
            accv[dt] = MFMA16(vf, pf, accv[dt]);
        }
    };

    for (int jt = 0; jt < ntiles; ++jt) {
        Kc = Ks[jt & 1];
        Vc = Vs[jt & 1];
        if (jt < qb) {
            #pragma unroll
            for (int js = 0; js < 4; ++js) subtile(jt, js, false);
        } else {
            for (int js = 0; js < wv; ++js) subtile(jt, js, false);
            subtile(jt, wv, true);
        }
        if (jt + 1 < ntiles) {
            ushort_t* Kw = Ks[(jt + 1) & 1];
            ushort_t* Vw = Vs[(jt + 1) & 1];
            *(uint4*)(Kw + sr * 72 + sc)     = ka0;
            *(uint4*)(Kw + sr * 72 + sc + 8) = ka1;
            *(uint4*)(Vw + sr * 72 + sc)     = va0;
            *(uint4*)(Vw + sr * 72 + sc + 8) = va1;
            if (jt + 2 < ntiles) {
                int j0n = (jt + 2) * 64;
                ka0 = *(const uint4*)(Kh + (size_t)(j0n + sr) * 64 + sc);
                ka1 = *(const uint4*)(Kh + (size_t)(j0n + sr) * 64 + sc + 8);
                va0 = *(const uint4*)(Vh + (size_t)sr * 2048 + j0n + sc);
                va1 = *(const uint4*)(Vh + (size_t)sr * 2048 + j0n + sc + 8);
            }
        }
        __syncthreads();
    }

    const float inv = 1.0f / fmaxf(accl[0], 1e-30f);
    const size_t obase = ((size_t)(b * 2048 + i_)) * 1024 + h * 64;
    #pragma unroll
    for (int dt = 0; dt < 4; ++dt) {
        ushort_t pk[4];
        #pragma unroll
        for (int r = 0; r < 4; ++r) pk[r] = f2bf(accv[dt][r] * inv);
        *(ushort2*)(AO + obase + dt * 16 + quad * 4)     = *(ushort2*)&pk[0];
        *(ushort2*)(AO + obase + dt * 16 + quad * 4 + 2) = *(ushort2*)&pk[2];
    }
}

// ---------------- Output projection GEMM + bias, global_load_lds -> FP32 ----------------
__global__ __launch_bounds__(256) void oproj_gemm(
    const ushort_t* __restrict__ A, const ushort_t* __restrict__ WT,
    const ushort_t* __restrict__ bias, float* __restrict__ out)
{
    __shared__ ushort_t As[128 * 32];
    __shared__ ushort_t Bs[128 * 32];

    const int tid  = threadIdx.x;
    const int m0   = blockIdx.y * 128, n0 = blockIdx.x * 128;
    const int lane = tid & 63, wv = tid >> 6;
    const int quad = lane >> 4, l15 = lane & 15;
    const int wm = (wv & 1) * 64, wn = (wv >> 1) * 64;

    const int lrow = lane >> 2;
    const int schk = (lane & 3) ^ ((lane >> 3) & 3);
    const int ra0_ = wv * 16 + lrow;
    ushort_t* aB0 = As + wv * 512;
    ushort_t* aB1 = As + 2048 + wv * 512;
    ushort_t* bB0 = Bs + wv * 512;
    ushort_t* bB1 = Bs + 2048 + wv * 512;
    const int sp = quad ^ ((l15 >> 1) & 3);

    f32x4 acc[4][4] = {};

    for (int kt = 0; kt < 32; ++kt) {
        const int k0 = kt * 32;
        __syncthreads();
        gl_lds16(A  + (size_t)(m0 + ra0_)      * 1024 + k0 + schk * 8, aB0);
        gl_lds16(A  + (size_t)(m0 + 64 + ra0_) * 1024 + k0 + schk * 8, aB1);
        gl_lds16(WT + (size_t)(n0 + ra0_)      * 1024 + k0 + schk * 8, bB0);
        gl_lds16(WT + (size_t)(n0 + 64 + ra0_) * 1024 + k0 + schk * 8, bB1);
        __syncthreads();

        bf16x8 af[4], bfr[4];
        #pragma unroll
        for (int t = 0; t < 4; ++t) {
            af[t]  = *(const bf16x8*)(As + (wm + t * 16 + l15) * 32 + sp * 8);
            bfr[t] = *(const bf16x8*)(Bs + (wn + t * 16 + l15) * 32 + sp * 8);
        }
        #pragma unroll
        for (int mt = 0; mt < 4; ++mt)
            #pragma unroll
            for (int nt = 0; nt < 4; ++nt)
                acc[mt][nt] = MFMA_16x16x32(af[mt], bfr[nt], acc[mt][nt]);
    }

    #pragma unroll
    for (int mt = 0; mt < 4; ++mt) {
        #pragma unroll
        for (int nt = 0; nt < 4; ++nt) {
            #pragma unroll
            for (int r = 0; r < 4; ++r) {
                int m = m0 + wm + mt * 16 + quad * 4 + r;
                int c = n0 + wn + nt * 16 + l15;
                out[(size_t)m * 1024 + c] = acc[mt][nt][r] + bf2f(bias[c]);
            }
        }
    }
}

extern "C" void kernel_launch(void* const* d_in, const int* in_sizes, int n_in,
                              void* d_out, int out_size, void* d_ws, size_t ws_size,
                              hipStream_t stream) {
    const void* X  = d_in[0];
    const void* Wq = d_in[1];
    const void* Wk = d_in[2];
    const void* Wv = d_in[3];
    const void* Wo = d_in[4];
    const void* bo = d_in[5];

    const size_t M = 1024 * 1024;
    ushort_t* ws  = (ushort_t*)d_ws;
    ushort_t* Qb  = ws;
    ushort_t* Kb  = ws + 4 * M;
    ushort_t* Vt  = ws + 8 * M;
    ushort_t* Xc  = ws + 12 * M;    // shared with AO (Xc dead after qkv_gemm)
    ushort_t* AO  = ws + 12 * M;
    ushort_t* WqT = ws + 16 * M;
    ushort_t* WkT = ws + 17 * M;
    ushort_t* WvT = ws + 18 * M;
    ushort_t* WoT = ws + 19 * M;
    ushort_t* boc = ws + 20 * M;
    float* out = (float*)d_out;

    convert_x<<<2049, 256, 0, stream>>>(X, Wq, bo, Xc, boc);
    transpose_w<<<dim3(16, 16, 4), 256, 0, stream>>>(Wq, Wk, Wv, Wo, WqT, WkT, WvT, WoT);
    qkv_gemm<<<dim3(8, 32, 3), 256, 0, stream>>>(Xc, WqT, WkT, WvT, Qb, Kb, Vt);
    attn_kernel<<<1024, 256, 0, stream>>>(Qb, Kb, Vt, AO);
    oproj_gemm<<<dim3(8, 32), 256, 0, stream>>>(AO, WoT, boc, out);
}

// Round 8
// 178.793 us; speedup vs baseline: 1.0649x; 1.0649x over previous
//
#include <hip/hip_runtime.h>
#include <hip/hip_bf16.h>

// B=2, N=2048, D=1024, H=16, DH=64. Output fp32; inputs runtime-detected and
// converted once. R12: qkv/oproj staging via global_load_lds width=16 + XOR
// chunk swizzle; attn diagonal-tile specialization.
// R14: attn ALiBi reach cap (sl2*j>46 tiles skipped; 0.54x work).
// R16/R18: XCD-grouped LPT schedule (sum-balance + L2 locality).
// R19 (dbuf): NEUTRAL -> per-tile chain is latency-exposed, not barrier-bound.
// Model fit (4 pts): tile ~0.6us at 4 blocks/CU, ~1.3us solo; attn time =
// max(sum-bound ~22us, longest-chain 32x1.3 ~42us). Chain is the binder.
// R20: split items with w>=16 into lo/hi half-chains in SEPARATE blocks
// (flash-decoding): each writes f32 partial accv/accl (linear in j -> exact
// merge); 238-pair merge kernel sums + normalizes -> AO. Max chain 16 tiles.
// Single-buffer 18KB LDS (6 blocks/CU resident). Grid 1536 (XCD-grouped LPT
// over 1262 sub-items; empty slots exit).
//
// ws (bf16 elems): Q@0(4M), K@4M, Vt@8M, Xc/AO@12M (shared), WqT@16M..WoT@19M,
// boc@20M, partials @22M (f32, ~8MB). ws >= 268MB per harness fill.

typedef __bf16 bf16x8 __attribute__((ext_vector_type(8)));
typedef float f32x4 __attribute__((ext_vector_type(4)));
typedef short s4 __attribute__((ext_vector_type(4)));      // k16 MFMA A/B frag
typedef unsigned short ushort_t;

#define MFMA_16x16x32(a, b, c) __builtin_amdgcn_mfma_f32_16x16x32_bf16(a, b, c, 0, 0, 0)
#define MFMA16(a, b, c) __builtin_amdgcn_mfma_f32_16x16x16bf16_1k(a, b, c, 0, 0, 0)

__device__ __forceinline__ ushort_t f2bf(float f) {
    __hip_bfloat16 h = __float2bfloat16(f);
    return __builtin_bit_cast(ushort_t, h);
}
__device__ __forceinline__ float bf2f(ushort_t u) {
    unsigned x = ((unsigned)u) << 16;
    return __builtin_bit_cast(float, x);
}

// async global->LDS, 16B/lane; LDS dest = wave-uniform base + lane*16.
__device__ __forceinline__ void gl_lds16(const ushort_t* g, ushort_t* l) {
    __builtin_amdgcn_global_load_lds(
        (const __attribute__((address_space(1))) void*)g,
        (__attribute__((address_space(3))) void*)l, 16, 0, 0);
}

__device__ __forceinline__ unsigned detect_fp32(const void* wp) {
    const ushort_t* w = (const ushort_t*)wp;
    unsigned c = 0;
    #pragma unroll
    for (int i = 0; i < 128; ++i) c += (((w[i] >> 7) & 0xFF) >= 0x7F) ? 1u : 0u;
    return (c > 8) ? 1u : 0u;
}

__device__ __forceinline__ uint4 load8(const void* p, size_t idx, unsigned flag) {
    if (flag) {
        const float* f = (const float*)p + idx;
        float4 a = *(const float4*)f;
        float4 b = *(const float4*)(f + 4);
        ushort_t u[8] = { f2bf(a.x), f2bf(a.y), f2bf(a.z), f2bf(a.w),
                          f2bf(b.x), f2bf(b.y), f2bf(b.z), f2bf(b.w) };
        return *(uint4*)u;
    }
    return *(const uint4*)((const ushort_t*)p + idx);
}

// ---- R20 schedule: slot -> packed sub-item; pair[k] -> (qb<<5)|bh ----
// Encoding: kind[1:0] (0 empty, 1 direct, 2 partial-lo, 3 partial-hi),
// bh[6:2], qb[11:7], jbeg[16:12], jend[22:17], k[30:23].
// XCD = slot%8 (HW round-robin), CU = (slot/8)%32, round = slot/256.
// Items with w>=16 split at w/2. Desc-work serpentine per XCD.
struct Sched { unsigned v[1536]; unsigned short pair[238]; };
constexpr Sched make_sched() {
    Sched s{};
    for (int i = 0; i < 1536; ++i) s.v[i] = 0;
    int jc[16] = {1, 1, 2, 2, 3, 4, 6, 8, 12, 16, 23, 32, 32, 32, 32, 32};
    int grp[8][4] = {
        {11, 12, 0, 2}, {13, 14, 1, 3}, {27, 28, 16, 18}, {29, 30, 17, 19},
        {15, 10, 5, 4}, {31, 26, 21, 20}, {9, 8, 7, 6}, {25, 24, 23, 22},
    };
    int np = 0;
    for (int x = 0; x < 8; ++x) {
        int sb_bh[200], sb_qb[200], sb_jb[200], sb_je[200], sb_kd[200], sb_k[200];
        int n = 0;
        for (int gi = 0; gi < 4; ++gi) {
            int bh = grp[x][gi], h = bh & 15;
            for (int qb = 0; qb < 32; ++qb) {
                int w = (qb + 1 < jc[h]) ? (qb + 1) : jc[h];
                if (w >= 16) {
                    int k = np++;
                    s.pair[k] = (unsigned short)((qb << 5) | bh);
                    int jm = w / 2;
                    sb_bh[n] = bh; sb_qb[n] = qb; sb_jb[n] = 0;  sb_je[n] = jm; sb_kd[n] = 2; sb_k[n] = k; ++n;
                    sb_bh[n] = bh; sb_qb[n] = qb; sb_jb[n] = jm; sb_je[n] = w;  sb_kd[n] = 3; sb_k[n] = k; ++n;
                } else {
                    sb_bh[n] = bh; sb_qb[n] = qb; sb_jb[n] = 0; sb_je[n] = w; sb_kd[n] = 1; sb_k[n] = 0; ++n;
                }
            }
        }
        int m = 0;
        for (int w = 16; w >= 1; --w)                   // counting sort, desc work
            for (int i2 = 0; i2 < n; ++i2)
                if (sb_je[i2] - sb_jb[i2] == w) {
                    int t = m++;
                    int r = t >> 5, p = t & 31;
                    int cu = (r & 1) ? (31 - p) : p;    // serpentine
                    s.v[r * 256 + cu * 8 + x] = (unsigned)(
                        sb_kd[i2] | (sb_bh[i2] << 2) | (sb_qb[i2] << 7) |
                        (sb_jb[i2] << 12) | (sb_je[i2] << 17) | (sb_k[i2] << 23));
                }
    }
    return s;
}
__constant__ Sched g_sched = make_sched();

// ---------------- convert X + bias ----------------
__global__ __launch_bounds__(256) void convert_x(
    const void* __restrict__ X, const void* __restrict__ Wq, const void* __restrict__ bo,
    ushort_t* __restrict__ Xc, ushort_t* __restrict__ boc)
{
    const unsigned flag = detect_fp32(Wq);
    const int blk = blockIdx.x;
    if (blk < 2048) {
        size_t idx = (size_t)blk * 2048 + (size_t)threadIdx.x * 8;
        *(uint4*)(Xc + idx) = load8(X, idx, flag);
    } else {
        size_t idx = (size_t)threadIdx.x * 8;
        if (idx < 1024) *(uint4*)(boc + idx) = load8(bo, idx, flag);
    }
}

// ---------------- transpose weights -> WT[n][k] ----------------
__global__ __launch_bounds__(256) void transpose_w(
    const void* __restrict__ Wq, const void* __restrict__ Wk,
    const void* __restrict__ Wv, const void* __restrict__ Wo,
    ushort_t* __restrict__ WqT, ushort_t* __restrict__ WkT,
    ushort_t* __restrict__ WvT, ushort_t* __restrict__ WoT)
{
    __shared__ ushort_t T[64][72];
    const unsigned flag = detect_fp32(Wq);
    const int z = blockIdx.z;
    const void* W = (z == 0) ? Wq : ((z == 1) ? Wk : ((z == 2) ? Wv : Wo));
    ushort_t* WT = (z == 0) ? WqT : ((z == 1) ? WkT : ((z == 2) ? WvT : WoT));

    const int k0 = blockIdx.y * 64, n0 = blockIdx.x * 64;
    const int r = threadIdx.x >> 2, c = (threadIdx.x & 3) * 16;

    *(uint4*)&T[r][c]     = load8(W, (size_t)(k0 + r) * 1024 + n0 + c,     flag);
    *(uint4*)&T[r][c + 8] = load8(W, (size_t)(k0 + r) * 1024 + n0 + c + 8, flag);
    __syncthreads();
    ushort_t tmp[16];
    #pragma unroll
    for (int j = 0; j < 16; ++j) tmp[j] = T[c + j][r];
    *(uint4*)(WT + (size_t)(n0 + r) * 1024 + k0 + c)     = *(uint4*)&tmp[0];
    *(uint4*)(WT + (size_t)(n0 + r) * 1024 + k0 + c + 8) = *(uint4*)&tmp[8];
}

// ---------------- QKV projection GEMM, 128x128, global_load_lds staging ----------------
__global__ __launch_bounds__(256) void qkv_gemm(
    const ushort_t* __restrict__ X, const ushort_t* __restrict__ WqT,
    const ushort_t* __restrict__ WkT, const ushort_t* __restrict__ WvT,
    ushort_t* __restrict__ Q, ushort_t* __restrict__ K, ushort_t* __restrict__ Vt)
{
    __shared__ ushort_t As[128 * 32];
    __shared__ ushort_t Bs[128 * 32];

    const int z = blockIdx.z;
    const ushort_t* WT = (z == 0) ? WqT : ((z == 1) ? WkT : WvT);

    const int tid  = threadIdx.x;
    const int m0   = blockIdx.y * 128, n0 = blockIdx.x * 128;
    const int lane = tid & 63, wv = tid >> 6;
    const int quad = lane >> 4, l15 = lane & 15;
    const int wm = (wv & 1) * 64, wn = (wv >> 1) * 64;

    const int lrow = lane >> 2;                         // 0..15
    const int schk = (lane & 3) ^ ((lane >> 3) & 3);    // swizzled source chunk
    const int ra0_ = wv * 16 + lrow;                    // issue-0 row
    ushort_t* aB0 = As + wv * 512;                      // wave-uniform LDS bases
    ushort_t* aB1 = As + 2048 + wv * 512;
    ushort_t* bB0 = Bs + wv * 512;
    ushort_t* bB1 = Bs + 2048 + wv * 512;
    const int sp = quad ^ ((l15 >> 1) & 3);             // read chunk position

    f32x4 acc[4][4] = {};

    for (int kt = 0; kt < 32; ++kt) {
        const int k0 = kt * 32;
        __syncthreads();
        gl_lds16(X  + (size_t)(m0 + ra0_)      * 1024 + k0 + schk * 8, aB0);
        gl_lds16(X  + (size_t)(m0 + 64 + ra0_) * 1024 + k0 + schk * 8, aB1);
        gl_lds16(WT + (size_t)(n0 + ra0_)      * 1024 + k0 + schk * 8, bB0);
        gl_lds16(WT + (size_t)(n0 + 64 + ra0_) * 1024 + k0 + schk * 8, bB1);
        __syncthreads();   // compiler emits vmcnt(0) drain -> LDS data visible

        bf16x8 af[4], bfr[4];
        #pragma unroll
        for (int t = 0; t < 4; ++t) {
            af[t]  = *(const bf16x8*)(As + (wm + t * 16 + l15) * 32 + sp * 8);
            bfr[t] = *(const bf16x8*)(Bs + (wn + t * 16 + l15) * 32 + sp * 8);
        }
        #pragma unroll
        for (int mt = 0; mt < 4; ++mt)
            #pragma unroll
            for (int nt = 0; nt < 4; ++nt)
                acc[mt][nt] = MFMA_16x16x32(af[mt], bfr[nt], acc[mt][nt]);
    }

    #pragma unroll
    for (int mt = 0; mt < 4; ++mt) {
        #pragma unroll
        for (int nt = 0; nt < 4; ++nt) {
            if (z == 2) {
                int c  = n0 + wn + nt * 16 + l15;
                int h  = c >> 6, dh = c & 63;
                int mA = m0 + wm + mt * 16 + quad * 4;
                int b  = mA >> 11, nseq = mA & 2047;
                ushort_t pk[4];
                #pragma unroll
                for (int r = 0; r < 4; ++r) pk[r] = f2bf(acc[mt][nt][r]);
                *(ushort2*)(Vt + ((size_t)((b * 16 + h) * 64 + dh)) * 2048 + nseq)     = *(ushort2*)&pk[0];
                *(ushort2*)(Vt + ((size_t)((b * 16 + h) * 64 + dh)) * 2048 + nseq + 2) = *(ushort2*)&pk[2];
            } else {
                ushort_t* dst = (z == 0) ? Q : K;
                #pragma unroll
                for (int r = 0; r < 4; ++r) {
                    int m = m0 + wm + mt * 16 + quad * 4 + r;
                    int c = n0 + wn + nt * 16 + l15;
                    int b = m >> 11, nseq = m & 2047;
                    int h = c >> 6, dh = c & 63;
                    dst[((size_t)((b * 16 + h) * 2048 + nseq)) * 64 + dh] = f2bf(acc[mt][nt][r]);
                }
            }
        }
    }
}

// ---------------- MFMA flash attention: split-chain sub-items ----------------
// grid 1536 flat, block 256 = 4 waves; sub-item from g_sched. kind 1 writes
// AO directly; kind 2/3 write f32 partials (accv raw + accl) for the merge.
// Partial sums are linear in j (softmax ref = j=0 globally) -> exact merge.
__global__ __launch_bounds__(256) void attn_kernel(
    const ushort_t* __restrict__ Q, const ushort_t* __restrict__ K,
    const ushort_t* __restrict__ Vt, ushort_t* __restrict__ AO,
    float* __restrict__ partV, float* __restrict__ partL)
{
    __shared__ ushort_t Ks[64 * 72];   // [j][d], stride 72
    __shared__ ushort_t Vs[64 * 72];   // [d][j], stride 72

    const unsigned e = g_sched.v[blockIdx.x];
    const int kind = e & 3;
    if (kind == 0) return;

    const int tid  = threadIdx.x;
    const int wv   = tid >> 6, lane = tid & 63;
    const int quad = lane >> 4, l15 = lane & 15;
    const int bh   = (e >> 2) & 31, h = bh & 15, b = bh >> 4;
    const int qb   = (e >> 7) & 31;
    const int jbeg = (e >> 12) & 31;
    const int jend = (e >> 17) & 63;
    const int pk_  = (e >> 23) & 255;
    const int iw   = qb * 64 + wv * 16;
    const int i_   = iw + l15;

    const ushort_t* Qh = Q  + (size_t)bh * 2048 * 64;
    const ushort_t* Kh = K  + (size_t)bh * 2048 * 64;
    const ushort_t* Vh = Vt + (size_t)bh * 64 * 2048;

    const float LOG2E = 1.44269504088896340736f;
    const float sl2 = exp2f(-0.5f * (float)(h + 1)) * LOG2E;
    const float c1  = 0.125f * LOG2E;

    bf16x8 qf0 = *(const bf16x8*)(Qh + (size_t)(iw + l15) * 64 + quad * 8);
    bf16x8 qf1 = *(const bf16x8*)(Qh + (size_t)(iw + l15) * 64 + 32 + quad * 8);

    s4 onesf;
    #pragma unroll
    for (int e2 = 0; e2 < 4; ++e2) onesf[e2] = (short)0x3F80;

    // per-lane bias base: -sl2*(quad*4+r); per-subtile only add -sl2*j0s.
    float nb[4];
    #pragma unroll
    for (int r = 0; r < 4; ++r) nb[r] = -sl2 * (float)(quad * 4 + r);

    f32x4 accv[4] = {};
    f32x4 accl = {};

    const int sr = tid >> 2, sc = (tid & 3) * 16;

    const int j0b = jbeg * 64;
    uint4 ka0 = *(const uint4*)(Kh + (size_t)(j0b + sr) * 64 + sc);
    uint4 ka1 = *(const uint4*)(Kh + (size_t)(j0b + sr) * 64 + sc + 8);
    uint4 va0 = *(const uint4*)(Vh + (size_t)sr * 2048 + j0b + sc);
    uint4 va1 = *(const uint4*)(Vh + (size_t)sr * 2048 + j0b + sc + 8);

    auto subtile = [&](int jt, int js, bool masked) {
        const int j0s = jt * 64 + js * 16;
        const float bj = -sl2 * (float)j0s;   // wave-uniform per subtile
        f32x4 sT = {};
        bf16x8 kf0 = *(const bf16x8*)(Ks + (js * 16 + l15) * 72 + quad * 8);
        bf16x8 kf1 = *(const bf16x8*)(Ks + (js * 16 + l15) * 72 + 32 + quad * 8);
        sT = MFMA_16x16x32(kf0, qf0, sT);
        sT = MFMA_16x16x32(kf1, qf1, sT);
        unsigned u[4];
        #pragma unroll
        for (int r = 0; r < 4; ++r) {
            float p = exp2f(fmaf(sT[r], c1, nb[r] + bj));
            if (masked && (j0s + quad * 4 + r) > i_) p = 0.0f;
            u[r] = __builtin_bit_cast(unsigned, p) + 0x8000u;
        }
        uint2 dd = { (u[0] >> 16) | (u[1] & 0xFFFF0000u),
                     (u[2] >> 16) | (u[3] & 0xFFFF0000u) };
        s4 pf = __builtin_bit_cast(s4, dd);
        accl = MFMA16(onesf, pf, accl);
        #pragma unroll
        for (int dt = 0; dt < 4; ++dt) {
            s4 vf = *(const s4*)(Vs + (dt * 16 + l15) * 72 + js * 16 + quad * 4);
            accv[dt] = MFMA16(vf, pf, accv[dt]);
        }
    };

    for (int jt = jbeg; jt < jend; ++jt) {
        __syncthreads();
        *(uint4*)(Ks + sr * 72 + sc)     = ka0;
        *(uint4*)(Ks + sr * 72 + sc + 8) = ka1;
        *(uint4*)(Vs + sr * 72 + sc)     = va0;
        *(uint4*)(Vs + sr * 72 + sc + 8) = va1;
        __syncthreads();
        if (jt + 1 < jend) {
            int j0n = (jt + 1) * 64;
            ka0 = *(const uint4*)(Kh + (size_t)(j0n + sr) * 64 + sc);
            ka1 = *(const uint4*)(Kh + (size_t)(j0n + sr) * 64 + sc + 8);
            va0 = *(const uint4*)(Vh + (size_t)sr * 2048 + j0n + sc);
            va1 = *(const uint4*)(Vh + (size_t)sr * 2048 + j0n + sc + 8);
        }
        if (jt < qb) {
            #pragma unroll
            for (int js = 0; js < 4; ++js) subtile(jt, js, false);
        } else {
            for (int js = 0; js < wv; ++js) subtile(jt, js, false);
            subtile(jt, wv, true);
        }
    }

    if (kind == 1) {
        const float inv = 1.0f / fmaxf(accl[0], 1e-30f);
        const size_t obase = ((size_t)(b * 2048 + i_)) * 1024 + h * 64;
        #pragma unroll
        for (int dt = 0; dt < 4; ++dt) {
            ushort_t pk2[4];
            #pragma unroll
            for (int r = 0; r < 4; ++r) pk2[r] = f2bf(accv[dt][r] * inv);
            *(ushort2*)(AO + obase + dt * 16 + quad * 4)     = *(ushort2*)&pk2[0];
            *(ushort2*)(AO + obase + dt * 16 + quad * 4 + 2) = *(ushort2*)&pk2[2];
        }
    } else {
        const int ps = 2 * pk_ + (kind == 3 ? 1 : 0);
        const int rl = wv * 16 + l15;                   // local row 0..63
        float* pv = partV + ((size_t)ps * 64 + rl) * 64;
        #pragma unroll
        for (int dt = 0; dt < 4; ++dt)
            *(f32x4*)(pv + dt * 16 + quad * 4) = accv[dt];
        partL[ps * 64 + rl] = accl[0];
    }
}

// ---------------- merge partial pairs -> AO ----------------
__global__ __launch_bounds__(256) void attn_merge(
    const float* __restrict__ partV, const float* __restrict__ partL,
    ushort_t* __restrict__ AO)
{
    const int p = blockIdx.x;
    const unsigned info = g_sched.pair[p];
    const int bh = info & 31, qb = info >> 5;
    const int b = bh >> 4, h = bh & 15;
    const int row = threadIdx.x >> 2, cg = (threadIdx.x & 3) * 16;

    const float* v0 = partV + ((size_t)(2 * p)     * 64 + row) * 64 + cg;
    const float* v1 = partV + ((size_t)(2 * p + 1) * 64 + row) * 64 + cg;
    const float l = partL[(2 * p) * 64 + row] + partL[(2 * p + 1) * 64 + row];
    const float inv = 1.0f / fmaxf(l, 1e-30f);

    ushort_t pk2[16];
    #pragma unroll
    for (int c = 0; c < 16; ++c) pk2[c] = f2bf((v0[c] + v1[c]) * inv);
    const size_t o = ((size_t)(b * 2048 + qb * 64 + row)) * 1024 + h * 64 + cg;
    *(uint4*)(AO + o)     = *(uint4*)&pk2[0];
    *(uint4*)(AO + o + 8) = *(uint4*)&pk2[8];
}

// ---------------- Output projection GEMM + bias, global_load_lds -> FP32 ----------------
__global__ __launch_bounds__(256) void oproj_gemm(
    const ushort_t* __restrict__ A, const ushort_t* __restrict__ WT,
    const ushort_t* __restrict__ bias, float* __restrict__ out)
{
    __shared__ ushort_t As[128 * 32];
    __shared__ ushort_t Bs[128 * 32];

    const int tid  = threadIdx.x;
    const int m0   = blockIdx.y * 128, n0 = blockIdx.x * 128;
    const int lane = tid & 63, wv = tid >> 6;
    const int quad = lane >> 4, l15 = lane & 15;
    const int wm = (wv & 1) * 64, wn = (wv >> 1) * 64;

    const int lrow = lane >> 2;
    const int schk = (lane & 3) ^ ((lane >> 3) & 3);
    const int ra0_ = wv * 16 + lrow;
    ushort_t* aB0 = As + wv * 512;
    ushort_t* aB1 = As + 2048 + wv * 512;
    ushort_t* bB0 = Bs + wv * 512;
    ushort_t* bB1 = Bs + 2048 + wv * 512;
    const int sp = quad ^ ((l15 >> 1) & 3);

    f32x4 acc[4][4] = {};

    for (int kt = 0; kt < 32; ++kt) {
        const int k0 = kt * 32;
        __syncthreads();
        gl_lds16(A  + (size_t)(m0 + ra0_)      * 1024 + k0 + schk * 8, aB0);
        gl_lds16(A  + (size_t)(m0 + 64 + ra0_) * 1024 + k0 + schk * 8, aB1);
        gl_lds16(WT + (size_t)(n0 + ra0_)      * 1024 + k0 + schk * 8, bB0);
        gl_lds16(WT + (size_t)(n0 + 64 + ra0_) * 1024 + k0 + schk * 8, bB1);
        __syncthreads();

        bf16x8 af[4], bfr[4];
        #pragma unroll
        for (int t = 0; t < 4; ++t) {
            af[t]  = *(const bf16x8*)(As + (wm + t * 16 + l15) * 32 + sp * 8);
            bfr[t] = *(const bf16x8*)(Bs + (wn + t * 16 + l15) * 32 + sp * 8);
        }
        #pragma unroll
        for (int mt = 0; mt < 4; ++mt)
            #pragma unroll
            for (int nt = 0; nt < 4; ++nt)
                acc[mt][nt] = MFMA_16x16x32(af[mt], bfr[nt], acc[mt][nt]);
    }

    #pragma unroll
    for (int mt = 0; mt < 4; ++mt) {
        #pragma unroll
        for (int nt = 0; nt < 4; ++nt) {
            #pragma unroll
            for (int r = 0; r < 4; ++r) {
                int m = m0 + wm + mt * 16 + quad * 4 + r;
                int c = n0 + wn + nt * 16 + l15;
                out[(size_t)m * 1024 + c] = acc[mt][nt][r] + bf2f(bias[c]);
            }
        }
    }
}

extern "C" void kernel_launch(void* const* d_in, const int* in_sizes, int n_in,
                              void* d_out, int out_size, void* d_ws, size_t ws_size,
                              hipStream_t stream) {
    const void* X  = d_in[0];
    const void* Wq = d_in[1];
    const void* Wk = d_in[2];
    const void* Wv = d_in[3];
    const void* Wo = d_in[4];
    const void* bo = d_in[5];

    const size_t M = 1024 * 1024;
    ushort_t* ws  = (ushort_t*)d_ws;
    ushort_t* Qb  = ws;
    ushort_t* Kb  = ws + 4 * M;
    ushort_t* Vt  = ws + 8 * M;
    ushort_t* Xc  = ws + 12 * M;    // shared with AO (Xc dead after qkv_gemm)
    ushort_t* AO  = ws + 12 * M;
    ushort_t* WqT = ws + 16 * M;
    ushort_t* WkT = ws + 17 * M;
    ushort_t* WvT = ws + 18 * M;
    ushort_t* WoT = ws + 19 * M;
    ushort_t* boc = ws + 20 * M;
    float* partV  = (float*)(ws + 22 * M);          // 476*64*64 f32 = 7.8MB
    float* partL  = partV + (size_t)476 * 64 * 64;  // 476*64 f32
    float* out = (float*)d_out;

    convert_x<<<2049, 256, 0, stream>>>(X, Wq, bo, Xc, boc);
    transpose_w<<<dim3(16, 16, 4), 256, 0, stream>>>(Wq, Wk, Wv, Wo, WqT, WkT, WvT, WoT);
    qkv_gemm<<<dim3(8, 32, 3), 256, 0, stream>>>(Xc, WqT, WkT, WvT, Qb, Kb, Vt);
    attn_kernel<<<1536, 256, 0, stream>>>(Qb, Kb, Vt, AO, partV, partL);
    attn_merge<<<238, 256, 0, stream>>>(partV, partL, AO);
    oproj_gemm<<<dim3(8, 32), 256, 0, stream>>>(AO, WoT, boc, out);
}

// Round 9
// 176.088 us; speedup vs baseline: 1.0813x; 1.0154x over previous
//
#include <hip/hip_runtime.h>
#include <hip/hip_bf16.h>

// B=2, N=2048, D=1024, H=16, DH=64. Output fp32; inputs runtime-detected and
// converted once. R12: qkv/oproj staging via global_load_lds width=16 + XOR
// chunk swizzle; attn diagonal-tile specialization.
// R14: attn ALiBi reach cap (sl2*j>46 tiles skipped; 0.54x work).
// R16/R18: XCD-grouped LPT schedule (sum-balance + L2 locality).
// R19 (dbuf): NEUTRAL -> per-tile chain latency-exposed, not barrier-bound.
// R20 WIN (186.5->178.8): flash-decoding split of w>=16 items into half-
// chains + exact f32 partial merge. Max chain 16 tiles.
// R21: (a) deeper split: all items w>=9 -> chains of <=8 tiles (1680
// sub-items, 1040 partial slots, 384 merge items of 2-4 partials); chain-
// bound 16x1.3~21us -> 8x1.3~10us, leaving the ~22us sum-bound floor.
// (b) convert_x + transpose_w fused into one prep kernel (1 launch saved).
//
// ws (bf16 elems): Q@0(4M), K@4M, Vt@8M, Xc/AO@12M (shared), WqT@16M..WoT@19M,
// boc@20M, partials @22M (f32: partV 17MB + partL). ws >= 268MB per harness.

typedef __bf16 bf16x8 __attribute__((ext_vector_type(8)));
typedef float f32x4 __attribute__((ext_vector_type(4)));
typedef short s4 __attribute__((ext_vector_type(4)));      // k16 MFMA A/B frag
typedef unsigned short ushort_t;

#define MFMA_16x16x32(a, b, c) __builtin_amdgcn_mfma_f32_16x16x32_bf16(a, b, c, 0, 0, 0)
#define MFMA16(a, b, c) __builtin_amdgcn_mfma_f32_16x16x16bf16_1k(a, b, c, 0, 0, 0)

__device__ __forceinline__ ushort_t f2bf(float f) {
    __hip_bfloat16 h = __float2bfloat16(f);
    return __builtin_bit_cast(ushort_t, h);
}
__device__ __forceinline__ float bf2f(ushort_t u) {
    unsigned x = ((unsigned)u) << 16;
    return __builtin_bit_cast(float, x);
}

// async global->LDS, 16B/lane; LDS dest = wave-uniform base + lane*16.
__device__ __forceinline__ void gl_lds16(const ushort_t* g, ushort_t* l) {
    __builtin_amdgcn_global_load_lds(
        (const __attribute__((address_space(1))) void*)g,
        (__attribute__((address_space(3))) void*)l, 16, 0, 0);
}

__device__ __forceinline__ unsigned detect_fp32(const void* wp) {
    const ushort_t* w = (const ushort_t*)wp;
    unsigned c = 0;
    #pragma unroll
    for (int i = 0; i < 128; ++i) c += (((w[i] >> 7) & 0xFF) >= 0x7F) ? 1u : 0u;
    return (c > 8) ? 1u : 0u;
}

__device__ __forceinline__ uint4 load8(const void* p, size_t idx, unsigned flag) {
    if (flag) {
        const float* f = (const float*)p + idx;
        float4 a = *(const float4*)f;
        float4 b = *(const float4*)(f + 4);
        ushort_t u[8] = { f2bf(a.x), f2bf(a.y), f2bf(a.z), f2bf(a.w),
                          f2bf(b.x), f2bf(b.y), f2bf(b.z), f2bf(b.w) };
        return *(uint4*)u;
    }
    return *(const uint4*)((const ushort_t*)p + idx);
}

// ---- R21 schedule. Sub-item encoding (32b):
// bh[4:0], qb[9:5], jbeg[14:10], jend[20:15], slot[31:21] (2047 = direct).
// e==0 (jend==0) marks an empty slot. Merge item mi: bh[4:0], qb[9:5],
// base[20:10], cnt[23:21]. XCD = slot%8, CU = (slot/8)%32, round = slot/256.
// All items with w>=9 split into ceil(w/8) balanced chains (<=8 tiles).
struct Sched { unsigned v[1792]; unsigned mi[384]; };
constexpr Sched make_sched() {
    Sched s{};
    for (int i = 0; i < 1792; ++i) s.v[i] = 0;
    for (int i = 0; i < 384; ++i) s.mi[i] = 0;
    int jc[16] = {1, 1, 2, 2, 3, 4, 6, 8, 12, 16, 23, 32, 32, 32, 32, 32};
    int grp[8][4] = {
        {11, 12, 0, 2}, {13, 14, 1, 3}, {27, 28, 16, 18}, {29, 30, 17, 19},
        {15, 10, 5, 4}, {31, 26, 21, 20}, {9, 8, 7, 6}, {25, 24, 23, 22},
    };
    int nslot = 0, nmi = 0;
    for (int x = 0; x < 8; ++x) {
        int sb_bh[256], sb_qb[256], sb_jb[256], sb_je[256], sb_sl[256];
        int n = 0;
        for (int gi = 0; gi < 4; ++gi) {
            int bh = grp[x][gi], h = bh & 15;
            for (int qb = 0; qb < 32; ++qb) {
                int w = (qb + 1 < jc[h]) ? (qb + 1) : jc[h];
                if (w >= 9) {
                    int nch = (w + 7) / 8;
                    s.mi[nmi++] = (unsigned)(bh | (qb << 5) | (nslot << 10) | (nch << 21));
                    int jb = 0;
                    for (int c = 0; c < nch; ++c) {
                        int je = jb + (w - jb) / (nch - c)
                               + (((w - jb) % (nch - c)) ? 1 : 0);
                        sb_bh[n] = bh; sb_qb[n] = qb; sb_jb[n] = jb;
                        sb_je[n] = je; sb_sl[n] = nslot++; ++n;
                        jb = je;
                    }
                } else {
                    sb_bh[n] = bh; sb_qb[n] = qb; sb_jb[n] = 0;
                    sb_je[n] = w; sb_sl[n] = 2047; ++n;
                }
            }
        }
        int m = 0;
        for (int w = 8; w >= 1; --w)                    // counting sort, desc len
            for (int i2 = 0; i2 < n; ++i2)
                if (sb_je[i2] - sb_jb[i2] == w) {
                    int t = m++;
                    int r = t >> 5, p = t & 31;
                    int cu = (r & 1) ? (31 - p) : p;    // serpentine
                    s.v[r * 256 + cu * 8 + x] = (unsigned)(
                        sb_bh[i2] | (sb_qb[i2] << 5) | (sb_jb[i2] << 10) |
                        (sb_je[i2] << 15) | (sb_sl[i2] << 21));
                }
    }
    return s;
}
__constant__ Sched g_sched = make_sched();

// ---------------- prep: convert X + bias + transpose weights (fused) ----------------
__global__ __launch_bounds__(256) void prep(
    const void* __restrict__ X, const void* __restrict__ Wq,
    const void* __restrict__ Wk, const void* __restrict__ Wv,
    const void* __restrict__ Wo, const void* __restrict__ bo,
    ushort_t* __restrict__ Xc, ushort_t* __restrict__ boc,
    ushort_t* __restrict__ WqT, ushort_t* __restrict__ WkT,
    ushort_t* __restrict__ WvT, ushort_t* __restrict__ WoT)
{
    __shared__ ushort_t T[64][72];
    const unsigned flag = detect_fp32(Wq);
    const int blk = blockIdx.x;
    if (blk < 2048) {
        size_t idx = (size_t)blk * 2048 + (size_t)threadIdx.x * 8;
        *(uint4*)(Xc + idx) = load8(X, idx, flag);
    } else if (blk == 2048) {
        size_t idx = (size_t)threadIdx.x * 8;
        if (idx < 1024) *(uint4*)(boc + idx) = load8(bo, idx, flag);
    } else {
        const int t = blk - 2049;                       // 0..1023
        const int z = t >> 8;
        const void* W = (z == 0) ? Wq : ((z == 1) ? Wk : ((z == 2) ? Wv : Wo));
        ushort_t* WT = (z == 0) ? WqT : ((z == 1) ? WkT : ((z == 2) ? WvT : WoT));
        const int k0 = ((t >> 4) & 15) * 64, n0 = (t & 15) * 64;
        const int r = threadIdx.x >> 2, c = (threadIdx.x & 3) * 16;

        *(uint4*)&T[r][c]     = load8(W, (size_t)(k0 + r) * 1024 + n0 + c,     flag);
        *(uint4*)&T[r][c + 8] = load8(W, (size_t)(k0 + r) * 1024 + n0 + c + 8, flag);
        __syncthreads();
        ushort_t tmp[16];
        #pragma unroll
        for (int j = 0; j < 16; ++j) tmp[j] = T[c + j][r];
        *(uint4*)(WT + (size_t)(n0 + r) * 1024 + k0 + c)     = *(uint4*)&tmp[0];
        *(uint4*)(WT + (size_t)(n0 + r) * 1024 + k0 + c + 8) = *(uint4*)&tmp[8];
    }
}

// ---------------- QKV projection GEMM, 128x128, global_load_lds staging ----------------
__global__ __launch_bounds__(256) void qkv_gemm(
    const ushort_t* __restrict__ X, const ushort_t* __restrict__ WqT,
    const ushort_t* __restrict__ WkT, const ushort_t* __restrict__ WvT,
    ushort_t* __restrict__ Q, ushort_t* __restrict__ K, ushort_t* __restrict__ Vt)
{
    __shared__ ushort_t As[128 * 32];
    __shared__ ushort_t Bs[128 * 32];

    const int z = blockIdx.z;
    const ushort_t* WT = (z == 0) ? WqT : ((z == 1) ? WkT : WvT);

    const int tid  = threadIdx.x;
    const int m0   = blockIdx.y * 128, n0 = blockIdx.x * 128;
    const int lane = tid & 63, wv = tid >> 6;
    const int quad = lane >> 4, l15 = lane & 15;
    const int wm = (wv & 1) * 64, wn = (wv >> 1) * 64;

    const int lrow = lane >> 2;                         // 0..15
    const int schk = (lane & 3) ^ ((lane >> 3) & 3);    // swizzled source chunk
    const int ra0_ = wv * 16 + lrow;                    // issue-0 row
    ushort_t* aB0 = As + wv * 512;                      // wave-uniform LDS bases
    ushort_t* aB1 = As + 2048 + wv * 512;
    ushort_t* bB0 = Bs + wv * 512;
    ushort_t* bB1 = Bs + 2048 + wv * 512;
    const int sp = quad ^ ((l15 >> 1) & 3);             // read chunk position

    f32x4 acc[4][4] = {};

    for (int kt = 0; kt < 32; ++kt) {
        const int k0 = kt * 32;
        __syncthreads();
        gl_lds16(X  + (size_t)(m0 + ra0_)      * 1024 + k0 + schk * 8, aB0);
        gl_lds16(X  + (size_t)(m0 + 64 + ra0_) * 1024 + k0 + schk * 8, aB1);
        gl_lds16(WT + (size_t)(n0 + ra0_)      * 1024 + k0 + schk * 8, bB0);
        gl_lds16(WT + (size_t)(n0 + 64 + ra0_) * 1024 + k0 + schk * 8, bB1);
        __syncthreads();   // compiler emits vmcnt(0) drain -> LDS data visible

        bf16x8 af[4], bfr[4];
        #pragma unroll
        for (int t = 0; t < 4; ++t) {
            af[t]  = *(const bf16x8*)(As + (wm + t * 16 + l15) * 32 + sp * 8);
            bfr[t] = *(const bf16x8*)(Bs + (wn + t * 16 + l15) * 32 + sp * 8);
        }
        #pragma unroll
        for (int mt = 0; mt < 4; ++mt)
            #pragma unroll
            for (int nt = 0; nt < 4; ++nt)
                acc[mt][nt] = MFMA_16x16x32(af[mt], bfr[nt], acc[mt][nt]);
    }

    #pragma unroll
    for (int mt = 0; mt < 4; ++mt) {
        #pragma unroll
        for (int nt = 0; nt < 4; ++nt) {
            if (z == 2) {
                int c  = n0 + wn + nt * 16 + l15;
                int h  = c >> 6, dh = c & 63;
                int mA = m0 + wm + mt * 16 + quad * 4;
                int b  = mA >> 11, nseq = mA & 2047;
                ushort_t pk[4];
                #pragma unroll
                for (int r = 0; r < 4; ++r) pk[r] = f2bf(acc[mt][nt][r]);
                *(ushort2*)(Vt + ((size_t)((b * 16 + h) * 64 + dh)) * 2048 + nseq)     = *(ushort2*)&pk[0];
                *(ushort2*)(Vt + ((size_t)((b * 16 + h) * 64 + dh)) * 2048 + nseq + 2) = *(ushort2*)&pk[2];
            } else {
                ushort_t* dst = (z == 0) ? Q : K;
                #pragma unroll
                for (int r = 0; r < 4; ++r) {
                    int m = m0 + wm + mt * 16 + quad * 4 + r;
                    int c = n0 + wn + nt * 16 + l15;
                    int b = m >> 11, nseq = m & 2047;
                    int h = c >> 6, dh = c & 63;
                    dst[((size_t)((b * 16 + h) * 2048 + nseq)) * 64 + dh] = f2bf(acc[mt][nt][r]);
                }
            }
        }
    }
}

// ---------------- MFMA flash attention: <=8-tile chains ----------------
// grid 1792 flat, block 256 = 4 waves; sub-item from g_sched. slot==2047
// writes AO directly; else writes f32 partials (accv raw + accl) at slot.
// Partial sums are linear in j (softmax ref = j=0 globally) -> exact merge.
__global__ __launch_bounds__(256) void attn_kernel(
    const ushort_t* __restrict__ Q, const ushort_t* __restrict__ K,
    const ushort_t* __restrict__ Vt, ushort_t* __restrict__ AO,
    float* __restrict__ partV, float* __restrict__ partL)
{
    __shared__ ushort_t Ks[64 * 72];   // [j][d], stride 72
    __shared__ ushort_t Vs[64 * 72];   // [d][j], stride 72

    const unsigned e = g_sched.v[blockIdx.x];
    const int jend = (e >> 15) & 63;
    if (jend == 0) return;                              // empty slot

    const int tid  = threadIdx.x;
    const int wv   = tid >> 6, lane = tid & 63;
    const int quad = lane >> 4, l15 = lane & 15;
    const int bh   = e & 31, h = bh & 15, b = bh >> 4;
    const int qb   = (e >> 5) & 31;
    const int jbeg = (e >> 10) & 31;
    const int slot = (e >> 21) & 2047;
    const int iw   = qb * 64 + wv * 16;
    const int i_   = iw + l15;

    const ushort_t* Qh = Q  + (size_t)bh * 2048 * 64;
    const ushort_t* Kh = K  + (size_t)bh * 2048 * 64;
    const ushort_t* Vh = Vt + (size_t)bh * 64 * 2048;

    const float LOG2E = 1.44269504088896340736f;
    const float sl2 = exp2f(-0.5f * (float)(h + 1)) * LOG2E;
    const float c1  = 0.125f * LOG2E;

    bf16x8 qf0 = *(const bf16x8*)(Qh + (size_t)(iw + l15) * 64 + quad * 8);
    bf16x8 qf1 = *(const bf16x8*)(Qh + (size_t)(iw + l15) * 64 + 32 + quad * 8);

    s4 onesf;
    #pragma unroll
    for (int e2 = 0; e2 < 4; ++e2) onesf[e2] = (short)0x3F80;

    // per-lane bias base: -sl2*(quad*4+r); per-subtile only add -sl2*j0s.
    float nb[4];
    #pragma unroll
    for (int r = 0; r < 4; ++r) nb[r] = -sl2 * (float)(quad * 4 + r);

    f32x4 accv[4] = {};
    f32x4 accl = {};

    const int sr = tid >> 2, sc = (tid & 3) * 16;

    const int j0b = jbeg * 64;
    uint4 ka0 = *(const uint4*)(Kh + (size_t)(j0b + sr) * 64 + sc);
    uint4 ka1 = *(const uint4*)(Kh + (size_t)(j0b + sr) * 64 + sc + 8);
    uint4 va0 = *(const uint4*)(Vh + (size_t)sr * 2048 + j0b + sc);
    uint4 va1 = *(const uint4*)(Vh + (size_t)sr * 2048 + j0b + sc + 8);

    auto subtile = [&](int jt, int js, bool masked) {
        const int j0s = jt * 64 + js * 16;
        const float bj = -sl2 * (float)j0s;   // wave-uniform per subtile
        f32x4 sT = {};
        bf16x8 kf0 = *(const bf16x8*)(Ks + (js * 16 + l15) * 72 + quad * 8);
        bf16x8 kf1 = *(const bf16x8*)(Ks + (js * 16 + l15) * 72 + 32 + quad * 8);
        sT = MFMA_16x16x32(kf0, qf0, sT);
        sT = MFMA_16x16x32(kf1, qf1, sT);
        unsigned u[4];
        #pragma unroll
        for (int r = 0; r < 4; ++r) {
            float p = exp2f(fmaf(sT[r], c1, nb[r] + bj));
            if (masked && (j0s + quad * 4 + r) > i_) p = 0.0f;
            u[r] = __builtin_bit_cast(unsigned, p) + 0x8000u;
        }
        uint2 dd = { (u[0] >> 16) | (u[1] & 0xFFFF0000u),
                     (u[2] >> 16) | (u[3] & 0xFFFF0000u) };
        s4 pf = __builtin_bit_cast(s4, dd);
        accl = MFMA16(onesf, pf, accl);
        #pragma unroll
        for (int dt = 0; dt < 4; ++dt) {
            s4 vf = *(const s4*)(Vs + (dt * 16 + l15) * 72 + js * 16 + quad * 4);
            accv[dt] = MFMA16(vf, pf, accv[dt]);
        }
    };

    for (int jt = jbeg; jt < jend; ++jt) {
        __syncthreads();
        *(uint4*)(Ks + sr * 72 + sc)     = ka0;
        *(uint4*)(Ks + sr * 72 + sc + 8) = ka1;
        *(uint4*)(Vs + sr * 72 + sc)     = va0;
        *(uint4*)(Vs + sr * 72 + sc + 8) = va1;
        __syncthreads();
        if (jt + 1 < jend) {
            int j0n = (jt + 1) * 64;
            ka0 = *(const uint4*)(Kh + (size_t)(j0n + sr) * 64 + sc);
            ka1 = *(const uint4*)(Kh + (size_t)(j0n + sr) * 64 + sc + 8);
            va0 = *(const uint4*)(Vh + (size_t)sr * 2048 + j0n + sc);
            va1 = *(const uint4*)(Vh + (size_t)sr * 2048 + j0n + sc + 8);
        }
        if (jt < qb) {
            #pragma unroll
            for (int js = 0; js < 4; ++js) subtile(jt, js, false);
        } else {
            for (int js = 0; js < wv; ++js) subtile(jt, js, false);
            subtile(jt, wv, true);
        }
    }

    if (slot == 2047) {
        const float inv = 1.0f / fmaxf(accl[0], 1e-30f);
        const size_t obase = ((size_t)(b * 2048 + i_)) * 1024 + h * 64;
        #pragma unroll
        for (int dt = 0; dt < 4; ++dt) {
            ushort_t pk2[4];
            #pragma unroll
            for (int r = 0; r < 4; ++r) pk2[r] = f2bf(accv[dt][r] * inv);
            *(ushort2*)(AO + obase + dt * 16 + quad * 4)     = *(ushort2*)&pk2[0];
            *(ushort2*)(AO + obase + dt * 16 + quad * 4 + 2) = *(ushort2*)&pk2[2];
        }
    } else {
        const int rl = wv * 16 + l15;                   // local row 0..63
        float* pv = partV + ((size_t)slot * 64 + rl) * 64;
        #pragma unroll
        for (int dt = 0; dt < 4; ++dt)
            *(f32x4*)(pv + dt * 16 + quad * 4) = accv[dt];
        partL[slot * 64 + rl] = accl[0];
    }
}

// ---------------- merge partial chains -> AO ----------------
__global__ __launch_bounds__(256) void attn_merge(
    const float* __restrict__ partV, const float* __restrict__ partL,
    ushort_t* __restrict__ AO)
{
    const unsigned info = g_sched.mi[blockIdx.x];
    const int bh = info & 31, qb = (info >> 5) & 31;
    const int base = (info >> 10) & 2047, cnt = (info >> 21) & 7;
    const int b = bh >> 4, h = bh & 15;
    const int row = threadIdx.x >> 2, cg = (threadIdx.x & 3) * 16;

    float acc[16] = {};
    float l = 0.0f;
    for (int c = 0; c < cnt; ++c) {
        const float* v = partV + ((size_t)(base + c) * 64 + row) * 64 + cg;
        #pragma unroll
        for (int j = 0; j < 16; ++j) acc[j] += v[j];
        l += partL[(base + c) * 64 + row];
    }
    const float inv = 1.0f / fmaxf(l, 1e-30f);

    ushort_t pk2[16];
    #pragma unroll
    for (int j = 0; j < 16; ++j) pk2[j] = f2bf(acc[j] * inv);
    const size_t o = ((size_t)(b * 2048 + qb * 64 + row)) * 1024 + h * 64 + cg;
    *(uint4*)(AO + o)     = *(uint4*)&pk2[0];
    *(uint4*)(AO + o + 8) = *(uint4*)&pk2[8];
}

// ---------------- Output projection GEMM + bias, global_load_lds -> FP32 ----------------
__global__ __launch_bounds__(256) void oproj_gemm(
    const ushort_t* __restrict__ A, const ushort_t* __restrict__ WT,
    const ushort_t* __restrict__ bias, float* __restrict__ out)
{
    __shared__ ushort_t As[128 * 32];
    __shared__ ushort_t Bs[128 * 32];

    const int tid  = threadIdx.x;
    const int m0   = blockIdx.y * 128, n0 = blockIdx.x * 128;
    const int lane = tid & 63, wv = tid >> 6;
    const int quad = lane >> 4, l15 = lane & 15;
    const int wm = (wv & 1) * 64, wn = (wv >> 1) * 64;

    const int lrow = lane >> 2;
    const int schk = (lane & 3) ^ ((lane >> 3) & 3);
    const int ra0_ = wv * 16 + lrow;
    ushort_t* aB0 = As + wv * 512;
    ushort_t* aB1 = As + 2048 + wv * 512;
    ushort_t* bB0 = Bs + wv * 512;
    ushort_t* bB1 = Bs + 2048 + wv * 512;
    const int sp = quad ^ ((l15 >> 1) & 3);

    f32x4 acc[4][4] = {};

    for (int kt = 0; kt < 32; ++kt) {
        const int k0 = kt * 32;
        __syncthreads();
        gl_lds16(A  + (size_t)(m0 + ra0_)      * 1024 + k0 + schk * 8, aB0);
        gl_lds16(A  + (size_t)(m0 + 64 + ra0_) * 1024 + k0 + schk * 8, aB1);
        gl_lds16(WT + (size_t)(n0 + ra0_)      * 1024 + k0 + schk * 8, bB0);
        gl_lds16(WT + (size_t)(n0 + 64 + ra0_) * 1024 + k0 + schk * 8, bB1);
        __syncthreads();

        bf16x8 af[4], bfr[4];
        #pragma unroll
        for (int t = 0; t < 4; ++t) {
            af[t]  = *(const bf16x8*)(As + (wm + t * 16 + l15) * 32 + sp * 8);
            bfr[t] = *(const bf16x8*)(Bs + (wn + t * 16 + l15) * 32 + sp * 8);
        }
        #pragma unroll
        for (int mt = 0; mt < 4; ++mt)
            #pragma unroll
            for (int nt = 0; nt < 4; ++nt)
                acc[mt][nt] = MFMA_16x16x32(af[mt], bfr[nt], acc[mt][nt]);
    }

    #pragma unroll
    for (int mt = 0; mt < 4; ++mt) {
        #pragma unroll
        for (int nt = 0; nt < 4; ++nt) {
            #pragma unroll
            for (int r = 0; r < 4; ++r) {
                int m = m0 + wm + mt * 16 + quad * 4 + r;
                int c = n0 + wn + nt * 16 + l15;
                out[(size_t)m * 1024 + c] = acc[mt][nt][r] + bf2f(bias[c]);
            }
        }
    }
}

extern "C" void kernel_launch(void* const* d_in, const int* in_sizes, int n_in,
                              void* d_out, int out_size, void* d_ws, size_t ws_size,
                              hipStream_t stream) {
    const void* X  = d_in[0];
    const void* Wq = d_in[1];
    const void* Wk = d_in[2];
    const void* Wv = d_in[3];
    const void* Wo = d_in[4];
    const void* bo = d_in[5];

    const size_t M = 1024 * 1024;
    ushort_t* ws  = (ushort_t*)d_ws;
    ushort_t* Qb  = ws;
    ushort_t* Kb  = ws + 4 * M;
    ushort_t* Vt  = ws + 8 * M;
    ushort_t* Xc  = ws + 12 * M;    // shared with AO (Xc dead after qkv_gemm)
    ushort_t* AO  = ws + 12 * M;
    ushort_t* WqT = ws + 16 * M;
    ushort_t* WkT = ws + 17 * M;
    ushort_t* WvT = ws + 18 * M;
    ushort_t* WoT = ws + 19 * M;
    ushort_t* boc = ws + 20 * M;
    float* partV  = (float*)(ws + 22 * M);           // 1040*64*64 f32 = 17MB
    float* partL  = partV + (size_t)1040 * 64 * 64;  // 1040*64 f32
    float* out = (float*)d_out;

    prep<<<3073, 256, 0, stream>>>(X, Wq, Wk, Wv, Wo, bo, Xc, boc, WqT, WkT, WvT, WoT);
    qkv_gemm<<<dim3(8, 32, 3), 256, 0, stream>>>(Xc, WqT, WkT, WvT, Qb, Kb, Vt);
    attn_kernel<<<1792, 256, 0, stream>>>(Qb, Kb, Vt, AO, partV, partL);
    attn_merge<<<384, 256, 0, stream>>>(partV, partL, AO);
    oproj_gemm<<<dim3(8, 32), 256, 0, stream>>>(AO, WoT, boc, out);
}